// Round 2
// baseline (445.681 us; speedup 1.0000x reference)
//
#include <hip/hip_runtime.h>
#include <math.h>

typedef unsigned short u16;
typedef __bf16 bf16x8 __attribute__((ext_vector_type(8)));
typedef float f32x4 __attribute__((ext_vector_type(4)));

__device__ __forceinline__ u16 f2bf(float f) {
  unsigned u = __float_as_uint(f);
  u += 0x7fff + ((u >> 16) & 1);   // RNE
  return (u16)(u >> 16);
}

__device__ __forceinline__ void gload_lds16(const void* g, void* l) {
  __builtin_amdgcn_global_load_lds(
      (const __attribute__((address_space(1))) unsigned int*)g,
      (__attribute__((address_space(3))) unsigned int*)l, 16, 0, 0);
}

// ---------------- fp32 -> bf16 convert (n = 4194304 fixed per launch config) --
__global__ __launch_bounds__(256) void k_cvt(const float* __restrict__ s,
                                             u16* __restrict__ d) {
  int i = (blockIdx.x * 256 + threadIdx.x) * 4;
  float4 v = *(const float4*)(s + i);
  ushort4 o;
  o.x = f2bf(v.x); o.y = f2bf(v.y); o.z = f2bf(v.z); o.w = f2bf(v.w);
  *(ushort4*)(d + i) = o;
}

// ---------------- GEMM: C[M,N] = A[M,K] * B[N,K]^T (+bias), bf16 in, fp32 out -
// 128x128 tile, BK=64, 4 waves (2x2 of 64x64), 16x16x32 bf16 MFMA. m97-style.
__global__ __launch_bounds__(256) void k_gemm_bt(const u16* __restrict__ A,
                                                 const u16* __restrict__ B,
                                                 const float* __restrict__ bias,
                                                 float* __restrict__ C,
                                                 int M, int N, int K) {
  __shared__ __align__(16) u16 As[128 * 64];
  __shared__ __align__(16) u16 Bs[128 * 64];
  const int tid = threadIdx.x;
  const int wid = tid >> 6, lane = tid & 63;
  const int lr = lane & 15, lg = lane >> 4;
  const int bm = blockIdx.y * 128, bn = blockIdx.x * 128;
  const int wm = (wid >> 1) * 64, wn = (wid & 1) * 64;
  f32x4 acc[4][4] = {};
  const int sr = tid >> 3, sc = (tid & 7) * 8;        // staging: 32 rows/issue
  const u16* ga = A + (size_t)(bm + sr) * K + sc;
  const u16* gb = B + (size_t)(bn + sr) * K + sc;
  char* ldsA = (char*)As + wid * 1024;                // wave-uniform LDS base
  char* ldsB = (char*)Bs + wid * 1024;
  for (int k0 = 0; k0 < K; k0 += 64) {
    __syncthreads();                                  // prev tile consumed
#pragma unroll
    for (int i = 0; i < 4; ++i) {
      gload_lds16(ga + (size_t)(i * 32) * K + k0, ldsA + i * 4096);
      gload_lds16(gb + (size_t)(i * 32) * K + k0, ldsB + i * 4096);
    }
    __syncthreads();                                  // drains vmcnt -> visible
#pragma unroll
    for (int kk = 0; kk < 2; ++kk) {
      bf16x8 af[4], bf[4];
#pragma unroll
      for (int mi = 0; mi < 4; ++mi)
        af[mi] = *(const bf16x8*)&As[(wm + mi * 16 + lr) * 64 + kk * 32 + lg * 8];
#pragma unroll
      for (int ni = 0; ni < 4; ++ni)
        bf[ni] = *(const bf16x8*)&Bs[(wn + ni * 16 + lr) * 64 + kk * 32 + lg * 8];
#pragma unroll
      for (int mi = 0; mi < 4; ++mi)
#pragma unroll
        for (int ni = 0; ni < 4; ++ni)
          acc[mi][ni] = __builtin_amdgcn_mfma_f32_16x16x32_bf16(af[mi], bf[ni],
                                                                acc[mi][ni], 0, 0, 0);
    }
  }
#pragma unroll
  for (int mi = 0; mi < 4; ++mi) {
#pragma unroll
    for (int ni = 0; ni < 4; ++ni) {
      int col = bn + wn + ni * 16 + lr;
      float bb = bias ? bias[col] : 0.0f;
#pragma unroll
      for (int j = 0; j < 4; ++j) {
        int row = bm + wm + mi * 16 + lg * 4 + j;
        C[(size_t)row * N + col] = acc[mi][ni][j] + bb;
      }
    }
  }
}

// ---------------- RMSNorm(+bias) + RoPE, fp32 in -> bf16 out -----------------
// grid (S, 2): y=0 -> q (cols 0..2047, pre-scaled by 1/sqrt(HD)), y=1 -> k
__global__ __launch_bounds__(256) void k_rmsnorm_rope(
    const float* __restrict__ qkv, const float* __restrict__ bq,
    const float* __restrict__ bk, const float* __restrict__ gq,
    const float* __restrict__ gk, const float* __restrict__ fcos,
    const float* __restrict__ fsin, u16* __restrict__ qb, u16* __restrict__ kb) {
  const int s = blockIdx.x, which = blockIdx.y;
  const int t = threadIdx.x;
  const float* src = qkv + (size_t)s * 6144 + which * 2048;
  const float* bias = which ? bk : bq;
  const float* g = which ? gk : gq;
  u16* dst = (which ? kb : qb) + (size_t)s * 2048;
  const int c0 = t * 8;
  float4 a0 = *(const float4*)(src + c0);
  float4 a1 = *(const float4*)(src + c0 + 4);
  float4 b0 = *(const float4*)(bias + c0);
  float4 b1 = *(const float4*)(bias + c0 + 4);
  float v[8];
  v[0] = a0.x + b0.x; v[1] = a0.y + b0.y; v[2] = a0.z + b0.z; v[3] = a0.w + b0.w;
  v[4] = a1.x + b1.x; v[5] = a1.y + b1.y; v[6] = a1.z + b1.z; v[7] = a1.w + b1.w;
  float ss = 0.f;
#pragma unroll
  for (int j = 0; j < 8; ++j) ss += v[j] * v[j];
#pragma unroll
  for (int m = 1; m < 64; m <<= 1) ss += __shfl_xor(ss, m);
  __shared__ float red[4];
  if ((t & 63) == 0) red[t >> 6] = ss;
  __syncthreads();
  float r = rsqrtf((red[0] + red[1] + red[2] + red[3]) * (1.0f / 2048.0f) + 1e-6f);
  // fold attention score scale 1/sqrt(128) into q (q only feeds QK^T)
  if (!which) r *= 0.08838834764831843f;
  float4 g0 = *(const float4*)(g + c0);
  float4 g1 = *(const float4*)(g + c0 + 4);
  float gg[8] = {g0.x, g0.y, g0.z, g0.w, g1.x, g1.y, g1.z, g1.w};
  const int p0 = (c0 & 127) >> 1;      // pair index within head
  u16 o[8];
#pragma unroll
  for (int j = 0; j < 4; ++j) {
    float a = v[2 * j] * r * gg[2 * j];
    float b = v[2 * j + 1] * r * gg[2 * j + 1];
    float co = fcos[s * 64 + p0 + j], si = fsin[s * 64 + p0 + j];
    o[2 * j]     = f2bf(a * co - b * si);
    o[2 * j + 1] = f2bf(a * si + b * co);
  }
  ushort4 q0; q0.x = o[0]; q0.y = o[1]; q0.z = o[2]; q0.w = o[3];
  ushort4 q1; q1.x = o[4]; q1.y = o[5]; q1.z = o[6]; q1.w = o[7];
  *(ushort4*)(dst + c0) = q0;
  *(ushort4*)(dst + c0 + 4) = q1;
}

// ---------------- V: bias + transpose -> vT[h*128+d][s] bf16 -----------------
__global__ __launch_bounds__(256) void k_transpose_v(const float* __restrict__ qkv,
                                                     const float* __restrict__ bv,
                                                     u16* __restrict__ vT) {
  __shared__ float tile[64][65];
  const int s0 = blockIdx.x * 64, d0 = blockIdx.y * 64;
  const int t = threadIdx.x;
  const int tc = (t & 15) * 4, tr = t >> 4;
  float4 bb = *(const float4*)(bv + d0 + tc);
#pragma unroll
  for (int i = 0; i < 4; ++i) {
    int sr = tr + i * 16;
    float4 x = *(const float4*)(qkv + (size_t)(s0 + sr) * 6144 + 4096 + d0 + tc);
    tile[sr][tc + 0] = x.x + bb.x;
    tile[sr][tc + 1] = x.y + bb.y;
    tile[sr][tc + 2] = x.z + bb.z;
    tile[sr][tc + 3] = x.w + bb.w;
  }
  __syncthreads();
#pragma unroll
  for (int i = 0; i < 4; ++i) {
    int dr = tr + i * 16;
    ushort4 o;
    o.x = f2bf(tile[tc + 0][dr]);
    o.y = f2bf(tile[tc + 1][dr]);
    o.z = f2bf(tile[tc + 2][dr]);
    o.w = f2bf(tile[tc + 3][dr]);
    *(ushort4*)(vT + (size_t)(d0 + dr) * 2048 + s0 + tc) = o;
  }
}

// ---------------- flash attention, k-split: grid (S/64, H, KSPLIT) -----------
// Each block: 4 waves x 16 q-rows, processes 1024 keys; writes unnormalized
// O (fp32) + per-row (m, l) partials to workspace.
__global__ __launch_bounds__(256) void k_attn(const u16* __restrict__ qb,
                                              const u16* __restrict__ kb,
                                              const u16* __restrict__ vT,
                                              float* __restrict__ opart,
                                              float* __restrict__ ml) {
  const int h = blockIdx.y, qt = blockIdx.x, ks = blockIdx.z;
  const int wid = threadIdx.x >> 6, lane = threadIdx.x & 63;
  const int lr = lane & 15, lg = lane >> 4;
  const int q0 = qt * 64 + wid * 16;
  __shared__ __align__(16) u16 P[4][16][72];   // wave-private P tiles, padded
  u16(*Pw)[72] = P[wid];
  bf16x8 qf[4];
#pragma unroll
  for (int kk = 0; kk < 4; ++kk)
    qf[kk] = *(const bf16x8*)(qb + (size_t)(q0 + lr) * 2048 + h * 128 + kk * 32 + lg * 8);
  f32x4 o[8] = {};
  float m[4] = {-3.0e38f, -3.0e38f, -3.0e38f, -3.0e38f};
  float lsum[4] = {0.f, 0.f, 0.f, 0.f};
  const int kbeg = ks * 1024, kend = kbeg + 1024;
  for (int k0 = kbeg; k0 < kend; k0 += 64) {
    f32x4 sf[4] = {};
#pragma unroll
    for (int nb = 0; nb < 4; ++nb)
#pragma unroll
      for (int kk = 0; kk < 4; ++kk) {
        bf16x8 kf = *(const bf16x8*)(kb + (size_t)(k0 + nb * 16 + lr) * 2048 +
                                     h * 128 + kk * 32 + lg * 8);
        sf[nb] = __builtin_amdgcn_mfma_f32_16x16x32_bf16(qf[kk], kf, sf[nb], 0, 0, 0);
      }
    float fv[4];
#pragma unroll
    for (int j = 0; j < 4; ++j) {
      float mm = fmaxf(fmaxf(sf[0][j], sf[1][j]), fmaxf(sf[2][j], sf[3][j]));
#pragma unroll
      for (int d = 1; d < 16; d <<= 1) mm = fmaxf(mm, __shfl_xor(mm, d, 16));
      float mn = fmaxf(m[j], mm);
      fv[j] = __expf(m[j] - mn);
      m[j] = mn;
    }
    float ps[4] = {0.f, 0.f, 0.f, 0.f};
#pragma unroll
    for (int nb = 0; nb < 4; ++nb)
#pragma unroll
      for (int j = 0; j < 4; ++j) {
        float p = __expf(sf[nb][j] - m[j]);
        sf[nb][j] = p;
        ps[j] += p;
      }
#pragma unroll
    for (int j = 0; j < 4; ++j) {
      float pp = ps[j];
#pragma unroll
      for (int d = 1; d < 16; d <<= 1) pp += __shfl_xor(pp, d, 16);
      lsum[j] = lsum[j] * fv[j] + pp;
    }
    f32x4 fvv;
    fvv[0] = fv[0]; fvv[1] = fv[1]; fvv[2] = fv[2]; fvv[3] = fv[3];
#pragma unroll
    for (int db = 0; db < 8; ++db) o[db] *= fvv;
    // P -> LDS (bf16); wave-private, compiler orders ds_write->ds_read
#pragma unroll
    for (int nb = 0; nb < 4; ++nb)
#pragma unroll
      for (int j = 0; j < 4; ++j)
        Pw[lg * 4 + j][nb * 16 + lr] = f2bf(sf[nb][j]);
#pragma unroll
    for (int kk = 0; kk < 2; ++kk) {
      bf16x8 pf = *(const bf16x8*)&Pw[lr][kk * 32 + lg * 8];
#pragma unroll
      for (int db = 0; db < 8; ++db) {
        bf16x8 vf = *(const bf16x8*)(vT + (size_t)(h * 128 + db * 16 + lr) * 2048 +
                                     k0 + kk * 32 + lg * 8);
        o[db] = __builtin_amdgcn_mfma_f32_16x16x32_bf16(pf, vf, o[db], 0, 0, 0);
      }
    }
  }
  // write unnormalized partials
  float* op = opart + ((size_t)ks * 32768 + (size_t)h * 2048 + q0) * 128;
#pragma unroll
  for (int db = 0; db < 8; ++db)
#pragma unroll
    for (int j = 0; j < 4; ++j)
      op[(size_t)(lg * 4 + j) * 128 + db * 16 + lr] = o[db][j];
  if (lr == 0) {
#pragma unroll
    for (int j = 0; j < 4; ++j) {
      float2 v2; v2.x = m[j]; v2.y = lsum[j];
      *(float2*)(ml + ((size_t)ks * 32768 + (size_t)h * 2048 + q0 + lg * 4 + j) * 2) = v2;
    }
  }
}

// ---------------- merge 2 k-split partials -> ao bf16 [s][h*128+d] -----------
__global__ __launch_bounds__(256) void k_attn_merge(const float* __restrict__ opart,
                                                    const float* __restrict__ ml,
                                                    u16* __restrict__ ob) {
  const int r = blockIdx.x * 8 + (threadIdx.x >> 5);   // r = h*2048 + q
  const int d0 = (threadIdx.x & 31) * 4;
  float2 ml0 = *(const float2*)(ml + (size_t)r * 2);
  float2 ml1 = *(const float2*)(ml + (size_t)(32768 + r) * 2);
  float M = fmaxf(ml0.x, ml1.x);
  float f0 = __expf(ml0.x - M), f1 = __expf(ml1.x - M);
  float inv = 1.0f / (ml0.y * f0 + ml1.y * f1);
  float4 a = *(const float4*)(opart + (size_t)r * 128 + d0);
  float4 b = *(const float4*)(opart + (size_t)(32768 + r) * 128 + d0);
  int h = r >> 11, q = r & 2047;
  ushort4 o;
  o.x = f2bf((a.x * f0 + b.x * f1) * inv);
  o.y = f2bf((a.y * f0 + b.y * f1) * inv);
  o.z = f2bf((a.z * f0 + b.z * f1) * inv);
  o.w = f2bf((a.w * f0 + b.w * f1) * inv);
  *(ushort4*)(ob + (size_t)q * 2048 + h * 128 + d0) = o;
}

// -----------------------------------------------------------------------------
extern "C" void kernel_launch(void* const* d_in, const int* in_sizes, int n_in,
                              void* d_out, int out_size, void* d_ws, size_t ws_size,
                              hipStream_t stream) {
  const float* x    = (const float*)d_in[0];
  const float* wq   = (const float*)d_in[1];
  const float* bq   = (const float*)d_in[2];
  const float* wk   = (const float*)d_in[3];
  const float* bk   = (const float*)d_in[4];
  const float* wv   = (const float*)d_in[5];
  const float* bv   = (const float*)d_in[6];
  const float* wo   = (const float*)d_in[7];
  const float* bo   = (const float*)d_in[8];
  const float* gq   = (const float*)d_in[9];
  const float* gk   = (const float*)d_in[10];
  const float* fcos = (const float*)d_in[11];
  const float* fsin = (const float*)d_in[12];

  // ws layout (92,274,688 B total; lifetime-overlapped):
  //   [0, 50331648)            qkv_pre fp32 (phase A) | opart+ml fp32 (attn)
  //   [50331648, 58720256)     xb bf16 (phase A)   | qb bf16 (phase B+)
  //   [58720256, 83886080)     wqkv bf16 (phase A) | kb, vT, ao bf16 (phase B+)
  //   [83886080, 92274688)     wob bf16 (whole call)
  char* ws = (char*)d_ws;
  float* qkv_pre = (float*)ws;
  float* opart = (float*)ws;                    // 2 x 32768 x 128 fp32 = 32 MB
  float* ml    = (float*)(ws + 33554432);       // 2 x 32768 x 2 fp32 = 512 KB
  u16* xb   = (u16*)(ws + 50331648);
  u16* wqkv = (u16*)(ws + 58720256);
  u16* qb   = (u16*)(ws + 50331648);
  u16* kb   = (u16*)(ws + 58720256);
  u16* vT   = (u16*)(ws + 67108864);
  u16* ao   = (u16*)(ws + 75497472);
  u16* wob  = (u16*)(ws + 83886080);

  k_cvt<<<4096, 256, 0, stream>>>(x, xb);
  k_cvt<<<4096, 256, 0, stream>>>(wq, wqkv);
  k_cvt<<<4096, 256, 0, stream>>>(wk, wqkv + 4194304);
  k_cvt<<<4096, 256, 0, stream>>>(wv, wqkv + 8388608);
  k_cvt<<<4096, 256, 0, stream>>>(wo, wob);

  // q|k|v = x @ [wq;wk;wv]^T  (bias applied downstream)
  k_gemm_bt<<<dim3(48, 16), 256, 0, stream>>>(xb, wqkv, nullptr, qkv_pre,
                                              2048, 6144, 2048);
  k_rmsnorm_rope<<<dim3(2048, 2), 256, 0, stream>>>(qkv_pre, bq, bk, gq, gk,
                                                    fcos, fsin, qb, kb);
  k_transpose_v<<<dim3(32, 32), 256, 0, stream>>>(qkv_pre, bv, vT);
  k_attn<<<dim3(32, 16, 2), 256, 0, stream>>>(qb, kb, vT, opart, ml);
  k_attn_merge<<<4096, 256, 0, stream>>>(opart, ml, ao);
  k_gemm_bt<<<dim3(16, 16), 256, 0, stream>>>(ao, wob, bo, (float*)d_out,
                                              2048, 2048, 2048);
}

// Round 3
// 266.222 us; speedup vs baseline: 1.6741x; 1.6741x over previous
//
#include <hip/hip_runtime.h>
#include <math.h>

typedef unsigned short u16;
typedef __bf16 bf16x8 __attribute__((ext_vector_type(8)));
typedef float f32x4 __attribute__((ext_vector_type(4)));

__device__ __forceinline__ u16 f2bf(float f) {
  unsigned u = __float_as_uint(f);
  u += 0x7fff + ((u >> 16) & 1);   // RNE
  return (u16)(u >> 16);
}

__device__ __forceinline__ void gload_lds16(const void* g, void* l) {
  __builtin_amdgcn_global_load_lds(
      (const __attribute__((address_space(1))) unsigned int*)g,
      (__attribute__((address_space(3))) unsigned int*)l, 16, 0, 0);
}

// ---------------- fp32 -> bf16 convert (n = 4194304 fixed per launch config) --
__global__ __launch_bounds__(256) void k_cvt(const float* __restrict__ s,
                                             u16* __restrict__ d) {
  int i = (blockIdx.x * 256 + threadIdx.x) * 4;
  float4 v = *(const float4*)(s + i);
  ushort4 o;
  o.x = f2bf(v.x); o.y = f2bf(v.y); o.z = f2bf(v.z); o.w = f2bf(v.w);
  *(ushort4*)(d + i) = o;
}

// ---------------- GEMM: C[M,N] = A[M,K] * B[N,K]^T (+bias), bf16 in, fp32 out -
// 128x128 tile, BK=64, 4 waves (2x2 of 64x64), 16x16x32 bf16 MFMA. m97-style.
__global__ __launch_bounds__(256) void k_gemm_bt(const u16* __restrict__ A,
                                                 const u16* __restrict__ B,
                                                 const float* __restrict__ bias,
                                                 float* __restrict__ C,
                                                 int M, int N, int K) {
  __shared__ __align__(16) u16 As[128 * 64];
  __shared__ __align__(16) u16 Bs[128 * 64];
  const int tid = threadIdx.x;
  const int wid = tid >> 6, lane = tid & 63;
  const int lr = lane & 15, lg = lane >> 4;
  const int bm = blockIdx.y * 128, bn = blockIdx.x * 128;
  const int wm = (wid >> 1) * 64, wn = (wid & 1) * 64;
  f32x4 acc[4][4] = {};
  const int sr = tid >> 3, sc = (tid & 7) * 8;        // staging: 32 rows/issue
  const u16* ga = A + (size_t)(bm + sr) * K + sc;
  const u16* gb = B + (size_t)(bn + sr) * K + sc;
  char* ldsA = (char*)As + wid * 1024;                // wave-uniform LDS base
  char* ldsB = (char*)Bs + wid * 1024;
  for (int k0 = 0; k0 < K; k0 += 64) {
    __syncthreads();                                  // prev tile consumed
#pragma unroll
    for (int i = 0; i < 4; ++i) {
      gload_lds16(ga + (size_t)(i * 32) * K + k0, ldsA + i * 4096);
      gload_lds16(gb + (size_t)(i * 32) * K + k0, ldsB + i * 4096);
    }
    __syncthreads();                                  // drains vmcnt -> visible
#pragma unroll
    for (int kk = 0; kk < 2; ++kk) {
      bf16x8 af[4], bf[4];
#pragma unroll
      for (int mi = 0; mi < 4; ++mi)
        af[mi] = *(const bf16x8*)&As[(wm + mi * 16 + lr) * 64 + kk * 32 + lg * 8];
#pragma unroll
      for (int ni = 0; ni < 4; ++ni)
        bf[ni] = *(const bf16x8*)&Bs[(wn + ni * 16 + lr) * 64 + kk * 32 + lg * 8];
#pragma unroll
      for (int mi = 0; mi < 4; ++mi)
#pragma unroll
        for (int ni = 0; ni < 4; ++ni)
          acc[mi][ni] = __builtin_amdgcn_mfma_f32_16x16x32_bf16(af[mi], bf[ni],
                                                                acc[mi][ni], 0, 0, 0);
    }
  }
#pragma unroll
  for (int mi = 0; mi < 4; ++mi) {
#pragma unroll
    for (int ni = 0; ni < 4; ++ni) {
      int col = bn + wn + ni * 16 + lr;
      float bb = bias ? bias[col] : 0.0f;
#pragma unroll
      for (int j = 0; j < 4; ++j) {
        int row = bm + wm + mi * 16 + lg * 4 + j;
        C[(size_t)row * N + col] = acc[mi][ni][j] + bb;
      }
    }
  }
}

// ---------------- RMSNorm(+bias) + RoPE, fp32 in -> bf16 out -----------------
// grid (S, 2): y=0 -> q (cols 0..2047, pre-scaled by 1/sqrt(HD)), y=1 -> k
__global__ __launch_bounds__(256) void k_rmsnorm_rope(
    const float* __restrict__ qkv, const float* __restrict__ bq,
    const float* __restrict__ bk, const float* __restrict__ gq,
    const float* __restrict__ gk, const float* __restrict__ fcos,
    const float* __restrict__ fsin, u16* __restrict__ qb, u16* __restrict__ kb) {
  const int s = blockIdx.x, which = blockIdx.y;
  const int t = threadIdx.x;
  const float* src = qkv + (size_t)s * 6144 + which * 2048;
  const float* bias = which ? bk : bq;
  const float* g = which ? gk : gq;
  u16* dst = (which ? kb : qb) + (size_t)s * 2048;
  const int c0 = t * 8;
  float4 a0 = *(const float4*)(src + c0);
  float4 a1 = *(const float4*)(src + c0 + 4);
  float4 b0 = *(const float4*)(bias + c0);
  float4 b1 = *(const float4*)(bias + c0 + 4);
  float v[8];
  v[0] = a0.x + b0.x; v[1] = a0.y + b0.y; v[2] = a0.z + b0.z; v[3] = a0.w + b0.w;
  v[4] = a1.x + b1.x; v[5] = a1.y + b1.y; v[6] = a1.z + b1.z; v[7] = a1.w + b1.w;
  float ss = 0.f;
#pragma unroll
  for (int j = 0; j < 8; ++j) ss += v[j] * v[j];
#pragma unroll
  for (int m = 1; m < 64; m <<= 1) ss += __shfl_xor(ss, m);
  __shared__ float red[4];
  if ((t & 63) == 0) red[t >> 6] = ss;
  __syncthreads();
  float r = rsqrtf((red[0] + red[1] + red[2] + red[3]) * (1.0f / 2048.0f) + 1e-6f);
  // fold attention score scale 1/sqrt(128) into q (q only feeds QK^T)
  if (!which) r *= 0.08838834764831843f;
  float4 g0 = *(const float4*)(g + c0);
  float4 g1 = *(const float4*)(g + c0 + 4);
  float gg[8] = {g0.x, g0.y, g0.z, g0.w, g1.x, g1.y, g1.z, g1.w};
  const int p0 = (c0 & 127) >> 1;      // pair index within head
  u16 o[8];
#pragma unroll
  for (int j = 0; j < 4; ++j) {
    float a = v[2 * j] * r * gg[2 * j];
    float b = v[2 * j + 1] * r * gg[2 * j + 1];
    float co = fcos[s * 64 + p0 + j], si = fsin[s * 64 + p0 + j];
    o[2 * j]     = f2bf(a * co - b * si);
    o[2 * j + 1] = f2bf(a * si + b * co);
  }
  ushort4 q0; q0.x = o[0]; q0.y = o[1]; q0.z = o[2]; q0.w = o[3];
  ushort4 q1; q1.x = o[4]; q1.y = o[5]; q1.z = o[6]; q1.w = o[7];
  *(ushort4*)(dst + c0) = q0;
  *(ushort4*)(dst + c0 + 4) = q1;
}

// ---------------- V: bias + transpose -> vT[h*128+d][s] bf16 -----------------
__global__ __launch_bounds__(256) void k_transpose_v(const float* __restrict__ qkv,
                                                     const float* __restrict__ bv,
                                                     u16* __restrict__ vT) {
  __shared__ float tile[64][65];
  const int s0 = blockIdx.x * 64, d0 = blockIdx.y * 64;
  const int t = threadIdx.x;
  const int tc = (t & 15) * 4, tr = t >> 4;
  float4 bb = *(const float4*)(bv + d0 + tc);
#pragma unroll
  for (int i = 0; i < 4; ++i) {
    int sr = tr + i * 16;
    float4 x = *(const float4*)(qkv + (size_t)(s0 + sr) * 6144 + 4096 + d0 + tc);
    tile[sr][tc + 0] = x.x + bb.x;
    tile[sr][tc + 1] = x.y + bb.y;
    tile[sr][tc + 2] = x.z + bb.z;
    tile[sr][tc + 3] = x.w + bb.w;
  }
  __syncthreads();
#pragma unroll
  for (int i = 0; i < 4; ++i) {
    int dr = tr + i * 16;
    ushort4 o;
    o.x = f2bf(tile[tc + 0][dr]);
    o.y = f2bf(tile[tc + 1][dr]);
    o.z = f2bf(tile[tc + 2][dr]);
    o.w = f2bf(tile[tc + 3][dr]);
    *(ushort4*)(vT + (size_t)(d0 + dr) * 2048 + s0 + tc) = o;
  }
}

// ---------------- flash attention, LDS-staged K/V, double-buffered -----------
// grid (512): block -> (h, qt) with head->XCD grouping. 4 waves x 16 q-rows.
// K tile [64 keys][128 d] and V tile [128 d][64 keys] staged via
// global_load_lds with XOR chunk swizzle (chunk ^= row&7), pre-swizzled on the
// GLOBAL source side (LDS dest must stay linear), un-swizzled on ds_read.
__global__ __launch_bounds__(256) void k_attn(const u16* __restrict__ qb,
                                              const u16* __restrict__ kb,
                                              const u16* __restrict__ vT,
                                              u16* __restrict__ ob) {
  __shared__ __align__(16) char Ks[2][16384];
  __shared__ __align__(16) char Vs[2][16384];
  __shared__ __align__(16) u16 P[4][16][72];   // wave-private P tiles, padded
  const int d = blockIdx.x;
  const int h = (d & 7) + ((d >> 8) << 3);     // XCD (~d%8) owns heads {x, x+8}
  const int qt = (d >> 3) & 31;
  const int tid = threadIdx.x;
  const int wid = tid >> 6, lane = tid & 63;
  const int lr = lane & 15, lg = lane >> 4;
  const int q0 = qt * 64 + wid * 16;
  u16(*Pw)[72] = P[wid];
  const char* kbB = (const char*)kb;
  const char* vTB = (const char*)vT;
  // staging source precompute (row&7 is invariant across issues)
  const int krow = tid >> 4;                   // K: 16 rows per issue
  const int kc = (tid & 15) ^ (krow & 7);      // pre-swizzled 16B chunk
  const int vrow = tid >> 3;                   // V: 32 rows per issue
  const int vc = (tid & 7) ^ (vrow & 7);
  char* ldsK = (char*)Ks + wid * 1024;         // wave-uniform dest bases
  char* ldsV = (char*)Vs + wid * 1024;

#define STAGE(buf, k0)                                                          \
  {                                                                             \
    _Pragma("unroll") for (int i = 0; i < 4; ++i)                               \
        gload_lds16(kbB + (size_t)((k0) + i * 16 + krow) * 4096 + h * 256 +     \
                        kc * 16,                                                \
                    ldsK + (buf) * 16384 + i * 4096);                           \
    _Pragma("unroll") for (int i = 0; i < 4; ++i)                               \
        gload_lds16(vTB + (size_t)(h * 128 + i * 32 + vrow) * 4096 + (k0) * 2 + \
                        vc * 16,                                                \
                    ldsV + (buf) * 16384 + i * 4096);                           \
  }

  bf16x8 qf[4];
#pragma unroll
  for (int kk = 0; kk < 4; ++kk)
    qf[kk] = *(const bf16x8*)(qb + (size_t)(q0 + lr) * 2048 + h * 128 + kk * 32 + lg * 8);
  f32x4 o[8] = {};
  float m[4] = {-3.0e38f, -3.0e38f, -3.0e38f, -3.0e38f};
  float lsum[4] = {0.f, 0.f, 0.f, 0.f};
  const int swz = lr & 7;                      // read-side un-swizzle key
  STAGE(0, 0);
  __syncthreads();                             // drains vmcnt(0)
  int cur = 0;
  for (int k0 = 0; k0 < 2048; k0 += 64) {
    if (k0 + 64 < 2048) STAGE(cur ^ 1, k0 + 64);
    const char* Kc = Ks[cur];
    const char* Vc = Vs[cur];
    f32x4 sf[4] = {};
    __builtin_amdgcn_s_setprio(1);
#pragma unroll
    for (int nb = 0; nb < 4; ++nb)
#pragma unroll
      for (int kk = 0; kk < 4; ++kk) {
        bf16x8 kf = *(const bf16x8*)(Kc + (nb * 16 + lr) * 256 +
                                     (((kk * 4 + lg) ^ swz) * 16));
        sf[nb] = __builtin_amdgcn_mfma_f32_16x16x32_bf16(qf[kk], kf, sf[nb], 0, 0, 0);
      }
    __builtin_amdgcn_s_setprio(0);
    float fv[4];
#pragma unroll
    for (int j = 0; j < 4; ++j) {
      float mm = fmaxf(fmaxf(sf[0][j], sf[1][j]), fmaxf(sf[2][j], sf[3][j]));
#pragma unroll
      for (int dd = 1; dd < 16; dd <<= 1) mm = fmaxf(mm, __shfl_xor(mm, dd, 16));
      float mn = fmaxf(m[j], mm);
      fv[j] = __expf(m[j] - mn);
      m[j] = mn;
    }
    float ps[4] = {0.f, 0.f, 0.f, 0.f};
#pragma unroll
    for (int nb = 0; nb < 4; ++nb)
#pragma unroll
      for (int j = 0; j < 4; ++j) {
        float p = __expf(sf[nb][j] - m[j]);
        sf[nb][j] = p;
        ps[j] += p;
      }
#pragma unroll
    for (int j = 0; j < 4; ++j) {
      float pp = ps[j];
#pragma unroll
      for (int dd = 1; dd < 16; dd <<= 1) pp += __shfl_xor(pp, dd, 16);
      lsum[j] = lsum[j] * fv[j] + pp;
    }
    f32x4 fvv;
    fvv[0] = fv[0]; fvv[1] = fv[1]; fvv[2] = fv[2]; fvv[3] = fv[3];
#pragma unroll
    for (int db = 0; db < 8; ++db) o[db] *= fvv;
    // P -> LDS (bf16); wave-private, compiler orders ds_write->ds_read
#pragma unroll
    for (int nb = 0; nb < 4; ++nb)
#pragma unroll
      for (int j = 0; j < 4; ++j)
        Pw[lg * 4 + j][nb * 16 + lr] = f2bf(sf[nb][j]);
    __builtin_amdgcn_s_setprio(1);
#pragma unroll
    for (int kk = 0; kk < 2; ++kk) {
      bf16x8 pf = *(const bf16x8*)&Pw[lr][kk * 32 + lg * 8];
#pragma unroll
      for (int db = 0; db < 8; ++db) {
        bf16x8 vf = *(const bf16x8*)(Vc + (db * 16 + lr) * 128 +
                                     (((kk * 4 + lg) ^ swz) * 16));
        o[db] = __builtin_amdgcn_mfma_f32_16x16x32_bf16(pf, vf, o[db], 0, 0, 0);
      }
    }
    __builtin_amdgcn_s_setprio(0);
    __syncthreads();                           // stage complete + bufs consumed
    cur ^= 1;
  }
#undef STAGE
  float inv[4];
#pragma unroll
  for (int j = 0; j < 4; ++j) inv[j] = 1.0f / lsum[j];
#pragma unroll
  for (int db = 0; db < 8; ++db)
#pragma unroll
    for (int j = 0; j < 4; ++j)
      ob[(size_t)(q0 + lg * 4 + j) * 2048 + h * 128 + db * 16 + lr] =
          f2bf(o[db][j] * inv[j]);
}

// -----------------------------------------------------------------------------
extern "C" void kernel_launch(void* const* d_in, const int* in_sizes, int n_in,
                              void* d_out, int out_size, void* d_ws, size_t ws_size,
                              hipStream_t stream) {
  const float* x    = (const float*)d_in[0];
  const float* wq   = (const float*)d_in[1];
  const float* bq   = (const float*)d_in[2];
  const float* wk   = (const float*)d_in[3];
  const float* bk   = (const float*)d_in[4];
  const float* wv   = (const float*)d_in[5];
  const float* bv   = (const float*)d_in[6];
  const float* wo   = (const float*)d_in[7];
  const float* bo   = (const float*)d_in[8];
  const float* gq   = (const float*)d_in[9];
  const float* gk   = (const float*)d_in[10];
  const float* fcos = (const float*)d_in[11];
  const float* fsin = (const float*)d_in[12];

  // ws layout (92,274,688 B total; lifetime-overlapped):
  //   [0, 50331648)            qkv_pre fp32 [2048][6144]
  //   [50331648, 58720256)     xb bf16 (phase A)   | qb bf16 (phase B+)
  //   [58720256, 83886080)     wqkv bf16 (phase A) | kb, vT, ao bf16 (phase B+)
  //   [83886080, 92274688)     wob bf16 (whole call)
  char* ws = (char*)d_ws;
  float* qkv_pre = (float*)ws;
  u16* xb   = (u16*)(ws + 50331648);
  u16* wqkv = (u16*)(ws + 58720256);
  u16* qb   = (u16*)(ws + 50331648);
  u16* kb   = (u16*)(ws + 58720256);
  u16* vT   = (u16*)(ws + 67108864);
  u16* ao   = (u16*)(ws + 75497472);
  u16* wob  = (u16*)(ws + 83886080);

  k_cvt<<<4096, 256, 0, stream>>>(x, xb);
  k_cvt<<<4096, 256, 0, stream>>>(wq, wqkv);
  k_cvt<<<4096, 256, 0, stream>>>(wk, wqkv + 4194304);
  k_cvt<<<4096, 256, 0, stream>>>(wv, wqkv + 8388608);
  k_cvt<<<4096, 256, 0, stream>>>(wo, wob);

  // q|k|v = x @ [wq;wk;wv]^T  (bias applied downstream)
  k_gemm_bt<<<dim3(48, 16), 256, 0, stream>>>(xb, wqkv, nullptr, qkv_pre,
                                              2048, 6144, 2048);
  k_rmsnorm_rope<<<dim3(2048, 2), 256, 0, stream>>>(qkv_pre, bq, bk, gq, gk,
                                                    fcos, fsin, qb, kb);
  k_transpose_v<<<dim3(32, 32), 256, 0, stream>>>(qkv_pre, bv, vT);
  k_attn<<<512, 256, 0, stream>>>(qb, kb, vT, ao);
  k_gemm_bt<<<dim3(16, 16), 256, 0, stream>>>(ao, wob, bo, (float*)d_out,
                                              2048, 2048, 2048);
}

// Round 4
// 240.886 us; speedup vs baseline: 1.8502x; 1.1052x over previous
//
#include <hip/hip_runtime.h>
#include <math.h>

typedef unsigned short u16;
typedef __bf16 bf16x8 __attribute__((ext_vector_type(8)));
typedef float f32x4 __attribute__((ext_vector_type(4)));

__device__ __forceinline__ u16 f2bf(float f) {
  unsigned u = __float_as_uint(f);
  u += 0x7fff + ((u >> 16) & 1);   // RNE
  return (u16)(u >> 16);
}

__device__ __forceinline__ void gload_lds16(const void* g, void* l) {
  __builtin_amdgcn_global_load_lds(
      (const __attribute__((address_space(1))) unsigned int*)g,
      (__attribute__((address_space(3))) unsigned int*)l, 16, 0, 0);
}

// ---------------- fp32 -> bf16 convert -----------------------------------------
__global__ __launch_bounds__(256) void k_cvt(const float* __restrict__ s,
                                             u16* __restrict__ d) {
  int i = (blockIdx.x * 256 + threadIdx.x) * 4;
  float4 v = *(const float4*)(s + i);
  ushort4 o;
  o.x = f2bf(v.x); o.y = f2bf(v.y); o.z = f2bf(v.z); o.w = f2bf(v.w);
  *(ushort4*)(d + i) = o;
}

// 4 weight matrices in one launch: y=0..2 -> d01 + y*4M (wq,wk,wv), y=3 -> d3 (wo)
__global__ __launch_bounds__(256) void k_cvt4(const float* __restrict__ s0,
                                              const float* __restrict__ s1,
                                              const float* __restrict__ s2,
                                              const float* __restrict__ s3,
                                              u16* __restrict__ d01,
                                              u16* __restrict__ d3) {
  const int y = blockIdx.y;
  const float* s = (y == 0) ? s0 : (y == 1) ? s1 : (y == 2) ? s2 : s3;
  u16* d = (y == 3) ? d3 : d01 + (size_t)y * 4194304;
  int i = (blockIdx.x * 256 + threadIdx.x) * 4;
  float4 v = *(const float4*)(s + i);
  ushort4 o;
  o.x = f2bf(v.x); o.y = f2bf(v.y); o.z = f2bf(v.z); o.w = f2bf(v.w);
  *(ushort4*)(d + i) = o;
}

// ---------------- big GEMM: C[M,N] = A[M,K] * B[N,K]^T, fp32 out ---------------
// 128x256 tile, BK=64, 512 thr (8 waves 2Mx4N, 64x64/wave). Counted-vmcnt
// double-buffered pipeline with raw s_barrier (no vmcnt(0) drain in loop).
// LDS tiles XOR-swizzled: chunk ^= row&7 (pre-swizzled global src, XOR'd read).
// Requires M%128==0, N%256==0, K%64==0, (N/256)%8==0. Grid: (M/128)*(N/256).
__global__ __launch_bounds__(512, 2) void k_gemm_big(const u16* __restrict__ A,
                                                     const u16* __restrict__ B,
                                                     float* __restrict__ C,
                                                     int M, int N, int K) {
  __shared__ __align__(16) char lds[2][49152];   // per buf: A 16K | B 32K
  const int tid = threadIdx.x;
  const int wid = tid >> 6, lane = tid & 63;
  const int lr = lane & 15, lg = lane >> 4;
  const int wm = (wid >> 2) * 64, wn = (wid & 3) * 64;
  // XCD swizzle: each XCD owns a contiguous group of bx columns (B-panel ~3MB
  // L2-resident), all by rows.
  const int nbx = N >> 8, nby = M >> 7;
  const int colsPerXcd = nbx >> 3;
  const int xcd = blockIdx.x & 7, idx = blockIdx.x >> 3;
  const int bx = xcd * colsPerXcd + idx / nby;
  const int by = idx % nby;
  const int bm = by * 128, bn = bx * 256;
  // staging: thread covers (srow + i*64, physical chunk tid&7); global source
  // chunk pre-swizzled so read-side XOR recovers linear data.
  const int srow = tid >> 3;
  const int schunk = (tid & 7) ^ (srow & 7);
  const size_t rsK = (size_t)K * 2;              // row stride, bytes
  const char* gA = (const char*)A + (size_t)(bm + srow) * rsK + schunk * 16;
  const char* gB = (const char*)B + (size_t)(bn + srow) * rsK + schunk * 16;
  char* dA = (char*)lds + wid * 1024;            // wave-uniform dest bases
  char* dB = (char*)lds + 16384 + wid * 1024;

#define STAGE(cur, k0)                                                         \
  {                                                                            \
    _Pragma("unroll") for (int i = 0; i < 2; ++i)                              \
        gload_lds16(gA + (size_t)(i * 64) * rsK + (size_t)(k0) * 2,            \
                    dA + (cur) * 49152 + i * 8192);                            \
    _Pragma("unroll") for (int i = 0; i < 4; ++i)                              \
        gload_lds16(gB + (size_t)(i * 64) * rsK + (size_t)(k0) * 2,            \
                    dB + (cur) * 49152 + i * 8192);                            \
  }

  f32x4 acc[4][4] = {};
  STAGE(0, 0);
  STAGE(1, 64);
  asm volatile("s_waitcnt vmcnt(6)" ::: "memory");   // tile0 landed
  __builtin_amdgcn_s_barrier();
  const int NT = K >> 6;
  int cur = 0;
  const int rsw = (lr & 7);                      // read-side swizzle key
  for (int t = 0; t < NT; ++t) {
    const char* La = (const char*)lds + cur * 49152;
    const char* Lb = La + 16384;
    bf16x8 af[4][2], bfr[4][2];
#pragma unroll
    for (int mi = 0; mi < 4; ++mi)
#pragma unroll
      for (int kk = 0; kk < 2; ++kk)
        af[mi][kk] = *(const bf16x8*)(La + (wm + mi * 16 + lr) * 128 +
                                      (((kk * 4 + lg) ^ rsw) * 16));
#pragma unroll
    for (int ni = 0; ni < 4; ++ni)
#pragma unroll
      for (int kk = 0; kk < 2; ++kk)
        bfr[ni][kk] = *(const bf16x8*)(Lb + (wn + ni * 16 + lr) * 128 +
                                       (((kk * 4 + lg) ^ rsw) * 16));
    asm volatile("s_waitcnt lgkmcnt(0)" ::: "memory");  // reads done pre-barrier
    __builtin_amdgcn_s_barrier();                       // all waves done w/ cur
    if (t + 2 < NT) STAGE(cur, (t + 2) << 6);           // overwrite cur (safe)
    __builtin_amdgcn_s_setprio(1);
#pragma unroll
    for (int kk = 0; kk < 2; ++kk)
#pragma unroll
      for (int mi = 0; mi < 4; ++mi)
#pragma unroll
        for (int ni = 0; ni < 4; ++ni)
          acc[mi][ni] = __builtin_amdgcn_mfma_f32_16x16x32_bf16(
              af[mi][kk], bfr[ni][kk], acc[mi][ni], 0, 0, 0);
    __builtin_amdgcn_s_setprio(0);
    if (t + 2 < NT)
      asm volatile("s_waitcnt vmcnt(6)" ::: "memory");  // t+1 landed, t+2 flying
    else
      asm volatile("s_waitcnt vmcnt(0)" ::: "memory");  // tail: drain
    __builtin_amdgcn_s_barrier();
    cur ^= 1;
  }
#undef STAGE
#pragma unroll
  for (int mi = 0; mi < 4; ++mi)
#pragma unroll
    for (int ni = 0; ni < 4; ++ni)
#pragma unroll
      for (int j = 0; j < 4; ++j)
        C[(size_t)(bm + wm + mi * 16 + lg * 4 + j) * N + bn + wn + ni * 16 + lr] =
            acc[mi][ni][j];
}

// ---------------- GEMM: C[M,N] = A[M,K] * B[N,K]^T (+bias), bf16 in, fp32 out -
// 128x128 tile, BK=64, 4 waves (2x2 of 64x64), 16x16x32 bf16 MFMA. m97-style.
__global__ __launch_bounds__(256) void k_gemm_bt(const u16* __restrict__ A,
                                                 const u16* __restrict__ B,
                                                 const float* __restrict__ bias,
                                                 float* __restrict__ C,
                                                 int M, int N, int K) {
  __shared__ __align__(16) u16 As[128 * 64];
  __shared__ __align__(16) u16 Bs[128 * 64];
  const int tid = threadIdx.x;
  const int wid = tid >> 6, lane = tid & 63;
  const int lr = lane & 15, lg = lane >> 4;
  const int bm = blockIdx.y * 128, bn = blockIdx.x * 128;
  const int wm = (wid >> 1) * 64, wn = (wid & 1) * 64;
  f32x4 acc[4][4] = {};
  const int sr = tid >> 3, sc = (tid & 7) * 8;        // staging: 32 rows/issue
  const u16* ga = A + (size_t)(bm + sr) * K + sc;
  const u16* gb = B + (size_t)(bn + sr) * K + sc;
  char* ldsA = (char*)As + wid * 1024;                // wave-uniform LDS base
  char* ldsB = (char*)Bs + wid * 1024;
  for (int k0 = 0; k0 < K; k0 += 64) {
    __syncthreads();                                  // prev tile consumed
#pragma unroll
    for (int i = 0; i < 4; ++i) {
      gload_lds16(ga + (size_t)(i * 32) * K + k0, ldsA + i * 4096);
      gload_lds16(gb + (size_t)(i * 32) * K + k0, ldsB + i * 4096);
    }
    __syncthreads();                                  // drains vmcnt -> visible
#pragma unroll
    for (int kk = 0; kk < 2; ++kk) {
      bf16x8 af[4], bf[4];
#pragma unroll
      for (int mi = 0; mi < 4; ++mi)
        af[mi] = *(const bf16x8*)&As[(wm + mi * 16 + lr) * 64 + kk * 32 + lg * 8];
#pragma unroll
      for (int ni = 0; ni < 4; ++ni)
        bf[ni] = *(const bf16x8*)&Bs[(wn + ni * 16 + lr) * 64 + kk * 32 + lg * 8];
#pragma unroll
      for (int mi = 0; mi < 4; ++mi)
#pragma unroll
        for (int ni = 0; ni < 4; ++ni)
          acc[mi][ni] = __builtin_amdgcn_mfma_f32_16x16x32_bf16(af[mi], bf[ni],
                                                                acc[mi][ni], 0, 0, 0);
    }
  }
#pragma unroll
  for (int mi = 0; mi < 4; ++mi) {
#pragma unroll
    for (int ni = 0; ni < 4; ++ni) {
      int col = bn + wn + ni * 16 + lr;
      float bb = bias ? bias[col] : 0.0f;
#pragma unroll
      for (int j = 0; j < 4; ++j) {
        int row = bm + wm + mi * 16 + lg * 4 + j;
        C[(size_t)row * N + col] = acc[mi][ni][j] + bb;
      }
    }
  }
}

// ---------------- RMSNorm(+bias) + RoPE, fp32 in -> bf16 out -----------------
// grid (S, 2): y=0 -> q (cols 0..2047, pre-scaled by 1/sqrt(HD)), y=1 -> k
__global__ __launch_bounds__(256) void k_rmsnorm_rope(
    const float* __restrict__ qkv, const float* __restrict__ bq,
    const float* __restrict__ bk, const float* __restrict__ gq,
    const float* __restrict__ gk, const float* __restrict__ fcos,
    const float* __restrict__ fsin, u16* __restrict__ qb, u16* __restrict__ kb) {
  const int s = blockIdx.x, which = blockIdx.y;
  const int t = threadIdx.x;
  const float* src = qkv + (size_t)s * 6144 + which * 2048;
  const float* bias = which ? bk : bq;
  const float* g = which ? gk : gq;
  u16* dst = (which ? kb : qb) + (size_t)s * 2048;
  const int c0 = t * 8;
  float4 a0 = *(const float4*)(src + c0);
  float4 a1 = *(const float4*)(src + c0 + 4);
  float4 b0 = *(const float4*)(bias + c0);
  float4 b1 = *(const float4*)(bias + c0 + 4);
  float v[8];
  v[0] = a0.x + b0.x; v[1] = a0.y + b0.y; v[2] = a0.z + b0.z; v[3] = a0.w + b0.w;
  v[4] = a1.x + b1.x; v[5] = a1.y + b1.y; v[6] = a1.z + b1.z; v[7] = a1.w + b1.w;
  float ss = 0.f;
#pragma unroll
  for (int j = 0; j < 8; ++j) ss += v[j] * v[j];
#pragma unroll
  for (int m = 1; m < 64; m <<= 1) ss += __shfl_xor(ss, m);
  __shared__ float red[4];
  if ((t & 63) == 0) red[t >> 6] = ss;
  __syncthreads();
  float r = rsqrtf((red[0] + red[1] + red[2] + red[3]) * (1.0f / 2048.0f) + 1e-6f);
  // fold attention score scale 1/sqrt(128) into q (q only feeds QK^T)
  if (!which) r *= 0.08838834764831843f;
  float4 g0 = *(const float4*)(g + c0);
  float4 g1 = *(const float4*)(g + c0 + 4);
  float gg[8] = {g0.x, g0.y, g0.z, g0.w, g1.x, g1.y, g1.z, g1.w};
  const int p0 = (c0 & 127) >> 1;      // pair index within head
  u16 o[8];
#pragma unroll
  for (int j = 0; j < 4; ++j) {
    float a = v[2 * j] * r * gg[2 * j];
    float b = v[2 * j + 1] * r * gg[2 * j + 1];
    float co = fcos[s * 64 + p0 + j], si = fsin[s * 64 + p0 + j];
    o[2 * j]     = f2bf(a * co - b * si);
    o[2 * j + 1] = f2bf(a * si + b * co);
  }
  ushort4 q0; q0.x = o[0]; q0.y = o[1]; q0.z = o[2]; q0.w = o[3];
  ushort4 q1; q1.x = o[4]; q1.y = o[5]; q1.z = o[6]; q1.w = o[7];
  *(ushort4*)(dst + c0) = q0;
  *(ushort4*)(dst + c0 + 4) = q1;
}

// ---------------- V: bias + transpose -> vT[h*128+d][s] bf16 -----------------
__global__ __launch_bounds__(256) void k_transpose_v(const float* __restrict__ qkv,
                                                     const float* __restrict__ bv,
                                                     u16* __restrict__ vT) {
  __shared__ float tile[64][65];
  const int s0 = blockIdx.x * 64, d0 = blockIdx.y * 64;
  const int t = threadIdx.x;
  const int tc = (t & 15) * 4, tr = t >> 4;
  float4 bb = *(const float4*)(bv + d0 + tc);
#pragma unroll
  for (int i = 0; i < 4; ++i) {
    int sr = tr + i * 16;
    float4 x = *(const float4*)(qkv + (size_t)(s0 + sr) * 6144 + 4096 + d0 + tc);
    tile[sr][tc + 0] = x.x + bb.x;
    tile[sr][tc + 1] = x.y + bb.y;
    tile[sr][tc + 2] = x.z + bb.z;
    tile[sr][tc + 3] = x.w + bb.w;
  }
  __syncthreads();
#pragma unroll
  for (int i = 0; i < 4; ++i) {
    int dr = tr + i * 16;
    ushort4 o;
    o.x = f2bf(tile[tc + 0][dr]);
    o.y = f2bf(tile[tc + 1][dr]);
    o.z = f2bf(tile[tc + 2][dr]);
    o.w = f2bf(tile[tc + 3][dr]);
    *(ushort4*)(vT + (size_t)(d0 + dr) * 2048 + s0 + tc) = o;
  }
}

// ---------------- flash attention, LDS-staged K/V, double-buffered -----------
// grid (512): block -> (h, qt) with head->XCD grouping. 4 waves x 16 q-rows.
__global__ __launch_bounds__(256) void k_attn(const u16* __restrict__ qb,
                                              const u16* __restrict__ kb,
                                              const u16* __restrict__ vT,
                                              u16* __restrict__ ob) {
  __shared__ __align__(16) char Ks[2][16384];
  __shared__ __align__(16) char Vs[2][16384];
  __shared__ __align__(16) u16 P[4][16][72];   // wave-private P tiles, padded
  const int d = blockIdx.x;
  const int h = (d & 7) + ((d >> 8) << 3);     // XCD (~d%8) owns heads {x, x+8}
  const int qt = (d >> 3) & 31;
  const int tid = threadIdx.x;
  const int wid = tid >> 6, lane = tid & 63;
  const int lr = lane & 15, lg = lane >> 4;
  const int q0 = qt * 64 + wid * 16;
  u16(*Pw)[72] = P[wid];
  const char* kbB = (const char*)kb;
  const char* vTB = (const char*)vT;
  const int krow = tid >> 4;                   // K: 16 rows per issue
  const int kc = (tid & 15) ^ (krow & 7);      // pre-swizzled 16B chunk
  const int vrow = tid >> 3;                   // V: 32 rows per issue
  const int vc = (tid & 7) ^ (vrow & 7);
  char* ldsK = (char*)Ks + wid * 1024;         // wave-uniform dest bases
  char* ldsV = (char*)Vs + wid * 1024;

#define STAGE(buf, k0)                                                          \
  {                                                                             \
    _Pragma("unroll") for (int i = 0; i < 4; ++i)                               \
        gload_lds16(kbB + (size_t)((k0) + i * 16 + krow) * 4096 + h * 256 +     \
                        kc * 16,                                                \
                    ldsK + (buf) * 16384 + i * 4096);                           \
    _Pragma("unroll") for (int i = 0; i < 4; ++i)                               \
        gload_lds16(vTB + (size_t)(h * 128 + i * 32 + vrow) * 4096 + (k0) * 2 + \
                        vc * 16,                                                \
                    ldsV + (buf) * 16384 + i * 4096);                           \
  }

  bf16x8 qf[4];
#pragma unroll
  for (int kk = 0; kk < 4; ++kk)
    qf[kk] = *(const bf16x8*)(qb + (size_t)(q0 + lr) * 2048 + h * 128 + kk * 32 + lg * 8);
  f32x4 o[8] = {};
  float m[4] = {-3.0e38f, -3.0e38f, -3.0e38f, -3.0e38f};
  float lsum[4] = {0.f, 0.f, 0.f, 0.f};
  const int swz = lr & 7;                      // read-side un-swizzle key
  STAGE(0, 0);
  __syncthreads();                             // drains vmcnt(0)
  int cur = 0;
  for (int k0 = 0; k0 < 2048; k0 += 64) {
    if (k0 + 64 < 2048) STAGE(cur ^ 1, k0 + 64);
    const char* Kc = Ks[cur];
    const char* Vc = Vs[cur];
    f32x4 sf[4] = {};
    __builtin_amdgcn_s_setprio(1);
#pragma unroll
    for (int nb = 0; nb < 4; ++nb)
#pragma unroll
      for (int kk = 0; kk < 4; ++kk) {
        bf16x8 kf = *(const bf16x8*)(Kc + (nb * 16 + lr) * 256 +
                                     (((kk * 4 + lg) ^ swz) * 16));
        sf[nb] = __builtin_amdgcn_mfma_f32_16x16x32_bf16(qf[kk], kf, sf[nb], 0, 0, 0);
      }
    __builtin_amdgcn_s_setprio(0);
    float fv[4];
#pragma unroll
    for (int j = 0; j < 4; ++j) {
      float mm = fmaxf(fmaxf(sf[0][j], sf[1][j]), fmaxf(sf[2][j], sf[3][j]));
#pragma unroll
      for (int dd = 1; dd < 16; dd <<= 1) mm = fmaxf(mm, __shfl_xor(mm, dd, 16));
      float mn = fmaxf(m[j], mm);
      fv[j] = __expf(m[j] - mn);
      m[j] = mn;
    }
    float ps[4] = {0.f, 0.f, 0.f, 0.f};
#pragma unroll
    for (int nb = 0; nb < 4; ++nb)
#pragma unroll
      for (int j = 0; j < 4; ++j) {
        float p = __expf(sf[nb][j] - m[j]);
        sf[nb][j] = p;
        ps[j] += p;
      }
#pragma unroll
    for (int j = 0; j < 4; ++j) {
      float pp = ps[j];
#pragma unroll
      for (int dd = 1; dd < 16; dd <<= 1) pp += __shfl_xor(pp, dd, 16);
      lsum[j] = lsum[j] * fv[j] + pp;
    }
    f32x4 fvv;
    fvv[0] = fv[0]; fvv[1] = fv[1]; fvv[2] = fv[2]; fvv[3] = fv[3];
#pragma unroll
    for (int db = 0; db < 8; ++db) o[db] *= fvv;
#pragma unroll
    for (int nb = 0; nb < 4; ++nb)
#pragma unroll
      for (int j = 0; j < 4; ++j)
        Pw[lg * 4 + j][nb * 16 + lr] = f2bf(sf[nb][j]);
    __builtin_amdgcn_s_setprio(1);
#pragma unroll
    for (int kk = 0; kk < 2; ++kk) {
      bf16x8 pf = *(const bf16x8*)&Pw[lr][kk * 32 + lg * 8];
#pragma unroll
      for (int db = 0; db < 8; ++db) {
        bf16x8 vf = *(const bf16x8*)(Vc + (db * 16 + lr) * 128 +
                                     (((kk * 4 + lg) ^ swz) * 16));
        o[db] = __builtin_amdgcn_mfma_f32_16x16x32_bf16(pf, vf, o[db], 0, 0, 0);
      }
    }
    __builtin_amdgcn_s_setprio(0);
    __syncthreads();                           // stage complete + bufs consumed
    cur ^= 1;
  }
#undef STAGE
  float inv[4];
#pragma unroll
  for (int j = 0; j < 4; ++j) inv[j] = 1.0f / lsum[j];
#pragma unroll
  for (int db = 0; db < 8; ++db)
#pragma unroll
    for (int j = 0; j < 4; ++j)
      ob[(size_t)(q0 + lg * 4 + j) * 2048 + h * 128 + db * 16 + lr] =
          f2bf(o[db][j] * inv[j]);
}

// -----------------------------------------------------------------------------
extern "C" void kernel_launch(void* const* d_in, const int* in_sizes, int n_in,
                              void* d_out, int out_size, void* d_ws, size_t ws_size,
                              hipStream_t stream) {
  const float* x    = (const float*)d_in[0];
  const float* wq   = (const float*)d_in[1];
  const float* bq   = (const float*)d_in[2];
  const float* wk   = (const float*)d_in[3];
  const float* bk   = (const float*)d_in[4];
  const float* wv   = (const float*)d_in[5];
  const float* bv   = (const float*)d_in[6];
  const float* wo   = (const float*)d_in[7];
  const float* bo   = (const float*)d_in[8];
  const float* gq   = (const float*)d_in[9];
  const float* gk   = (const float*)d_in[10];
  const float* fcos = (const float*)d_in[11];
  const float* fsin = (const float*)d_in[12];

  // ws layout (92,274,688 B total; lifetime-overlapped):
  //   [0, 50331648)            qkv_pre fp32 [2048][6144]
  //   [50331648, 58720256)     xb bf16 (phase A)   | qb bf16 (phase B+)
  //   [58720256, 83886080)     wqkv bf16 (phase A) | kb, vT, ao bf16 (phase B+)
  //   [83886080, 92274688)     wob bf16 (whole call)
  char* ws = (char*)d_ws;
  float* qkv_pre = (float*)ws;
  u16* xb   = (u16*)(ws + 50331648);
  u16* wqkv = (u16*)(ws + 58720256);
  u16* qb   = (u16*)(ws + 50331648);
  u16* kb   = (u16*)(ws + 58720256);
  u16* vT   = (u16*)(ws + 67108864);
  u16* ao   = (u16*)(ws + 75497472);
  u16* wob  = (u16*)(ws + 83886080);

  k_cvt<<<4096, 256, 0, stream>>>(x, xb);
  k_cvt4<<<dim3(4096, 4), 256, 0, stream>>>(wq, wk, wv, wo, wqkv, wob);

  // q|k|v = x @ [wq;wk;wv]^T  (bias applied downstream)
  k_gemm_big<<<384, 512, 0, stream>>>(xb, wqkv, qkv_pre, 2048, 6144, 2048);
  k_rmsnorm_rope<<<dim3(2048, 2), 256, 0, stream>>>(qkv_pre, bq, bk, gq, gk,
                                                    fcos, fsin, qb, kb);
  k_transpose_v<<<dim3(32, 32), 256, 0, stream>>>(qkv_pre, bv, vT);
  k_attn<<<512, 256, 0, stream>>>(qb, kb, vT, ao);
  k_gemm_bt<<<dim3(16, 16), 256, 0, stream>>>(ao, wob, bo, (float*)d_out,
                                              2048, 2048, 2048);
}